// Round 19
// baseline (71.864 us; speedup 1.0000x reference)
//
#include <hip/hip_runtime.h>

#define NS 128
#define NX 512
#define NY 512
#define NT 2048
#define WIN 64          // per-sensor LDS window (pow2)
#define TI 16           // tile rows
#define TJ 16           // tile cols

// ===== NUMERICS CONTRACT (R2/R4/R10/R12/R16/R17/R19 failed; R0/R3/R5-R9/
// R11/R13-R15 passed) =====
// floor(idx) must match the np reference everywhere. The ONLY passing DAG,
// SCALAR, PER PIXEL with its OWN single-use dx,dy pair from its OWN loads:
//     dxk = gk.x - svx;  dyk = gk.y - svy;   // gk loaded per pixel (float2)
//     d2k = dxk*dxk + dyk*dyk;               // literal text, single use
//     distk = sqrt_cr(d2k);                  // Tuckerman fence LOAD-BEARING
//     idxk = distk * (1.0f/1500.0f) * (1.0f/4e-08f);
// FORBIDDEN (each with a failing round):
//   - folded scale inside sqrt (R2)
//   - raw v_sqrt for idx (R19: gfx950 v_sqrt is NOT correctly rounded)
//   - float2/packed math on the idx path (R4, R12)
//   - hand-pinned fmaf contraction (R16)
//   - sharing dy/gy VALUES across pixels (R17: multi-use dy*dy ->
//     form-A contraction). Separate loads of bit-equal values are SAFE
//     (R14 passed: same-column pixels, separate float2 loads).
// Window coverage (WIN=64, any pixel of a 16x16 tile vs ref px (8,8)):
// |didx| <= 14.77 samples; ws=(int)idxc-31 -> slot e in [15,47], e+1 <= 48.
// idx in [361,1306] -> staging always in-bounds.
//
// R20 EXPERIMENT: untested cell of the {ILP, occupancy} matrix — 4 px/lane
// AT full 32 waves/CU (R9's 4px ran at 16 waves/CU and lost). Attacks the
// ~25% stall fraction; VALU count per px-sensor unchanged.

__device__ __forceinline__ float sqrt_cr(float x) {
    const float r0 = __builtin_amdgcn_sqrtf(x);               // <=1 ulp
    const float rd = __int_as_float(__float_as_int(r0) - 1);
    const float ru = __int_as_float(__float_as_int(r0) + 1);
    const float vd = fmaf(-rd, r0, x);
    const float vu = fmaf(-ru, r0, x);
    float r = (vd <= 0.0f) ? rd : r0;
    r = (vu > 0.0f) ? ru : r;
    return r;
}

__global__ __launch_bounds__(512, 8) void das_kernel(
        const float* __restrict__ x,        // (NS, NT)
        const float* __restrict__ sensors,  // (NS, 2)
        const float* __restrict__ grid,     // (P, 2)
        float* __restrict__ out) {          // (P,)
    __shared__ float4 rec[NS];              // {sx, sy, ldsoff bits, gbase bits}
    __shared__ float win[NS * WIN];         // 32 KB sample windows
    __shared__ float part[2][512];

    const int tid = threadIdx.x;
    const int bi = blockIdx.x;              // 1024 blocks
    const int ti = bi >> 5;                 // 0..31
    const int tj = bi & 31;                 // 0..31

    // --- phase 1: per-sensor record from tile reference pixel (8,8)
    if (tid < NS) {
        const float2 sv = reinterpret_cast<const float2*>(sensors)[tid];
        const float2 gc = reinterpret_cast<const float2*>(
            grid)[(ti * TI + 8) * NY + (tj * TJ + 8)];
        const float dx = gc.x - sv.x;
        const float dy = gc.y - sv.y;
        const float idxc = __builtin_amdgcn_sqrtf(dx * dx + dy * dy)
                           * (1.0f / 1500.0f) * (1.0f / 4e-08f);
        const int ws = (int)idxc - 31;      // window covers ws .. ws+63
        rec[tid] = make_float4(sv.x, sv.y,
                               __int_as_float(tid * WIN - ws),
                               __int_as_float(tid * NT + ws));
    }
    __syncthreads();

    // --- phase 2: stage windows; each of 8 waves stages one sensor/round
    const int wv = tid >> 6;                // wave 0..7
    const int lane = tid & 63;
#pragma unroll
    for (int r = 0; r < NS / 8; ++r) {
        const int s = r * 8 + wv;
        const int gb = __float_as_int(rec[s].w);   // uniform LDS broadcast
        win[s * WIN + lane] = x[gb + lane];        // 256B coalesced row copy
    }
    __syncthreads();

    // --- main loop: 4 pixels per lane (same column, rows +0/+4/+8/+12),
    // 16 sensors per wave (8-way sensor split), full 32 waves/CU.
    const int col = tj * TJ + (lane & 15);
    const int row0 = ti * TI + (lane >> 4);
    const int pbase = row0 * NY + col;

    // FOUR SEPARATE full float2 loads — no component sharing (R17 lesson)
    const float2 g0 = reinterpret_cast<const float2*>(grid)[pbase];
    const float2 g1 = reinterpret_cast<const float2*>(grid)[pbase + 4 * NY];
    const float2 g2 = reinterpret_cast<const float2*>(grid)[pbase + 8 * NY];
    const float2 g3 = reinterpret_cast<const float2*>(grid)[pbase + 12 * NY];

    const float inv_c = 1.0f / 1500.0f;
    const float inv_dt = 1.0f / 4e-08f;

    const int sbase = __builtin_amdgcn_readfirstlane(wv << 4);
    const float4* recp = rec + sbase;

    float aA0 = 0.0f, aB0 = 0.0f, aA1 = 0.0f, aB1 = 0.0f;
    float aA2 = 0.0f, aB2 = 0.0f, aA3 = 0.0f, aB3 = 0.0f;
#pragma unroll
    for (int s = 0; s < 16; ++s) {
        const float4 rc = recp[s];                 // ds_read_b128, uniform
        const float svx = rc.x;
        const float svy = rc.y;
        const int o = __float_as_int(rc.z);        // window element offset

        // px0 — FROZEN DAG (R14 text verbatim)
        const float dx0 = g0.x - svx;
        const float dy0 = g0.y - svy;
        const float dist0 = sqrt_cr(dx0 * dx0 + dy0 * dy0);
        const float idx0 = dist0 * inv_c * inv_dt;
        const int i00 = (int)idx0;
        const float w00 = __builtin_amdgcn_fractf(idx0);
        // px1
        const float dx1 = g1.x - svx;
        const float dy1 = g1.y - svy;
        const float dist1 = sqrt_cr(dx1 * dx1 + dy1 * dy1);
        const float idx1 = dist1 * inv_c * inv_dt;
        const int i10 = (int)idx1;
        const float w10 = __builtin_amdgcn_fractf(idx1);
        // px2
        const float dx2 = g2.x - svx;
        const float dy2 = g2.y - svy;
        const float dist2 = sqrt_cr(dx2 * dx2 + dy2 * dy2);
        const float idx2 = dist2 * inv_c * inv_dt;
        const int i20 = (int)idx2;
        const float w20 = __builtin_amdgcn_fractf(idx2);
        // px3
        const float dx3 = g3.x - svx;
        const float dy3 = g3.y - svy;
        const float dist3 = sqrt_cr(dx3 * dx3 + dy3 * dy3);
        const float idx3 = dist3 * inv_c * inv_dt;
        const int i30 = (int)idx3;
        const float w30 = __builtin_amdgcn_fractf(idx3);

        const float* wp0 = &win[i00 + o];          // ds_read2_b32 each
        const float* wp1 = &win[i10 + o];
        const float* wp2 = &win[i20 + o];
        const float* wp3 = &win[i30 + o];
        const float y00 = wp0[0], y01 = wp0[1];
        const float y10 = wp1[0], y11 = wp1[1];
        const float y20 = wp2[0], y21 = wp2[1];
        const float y30 = wp3[0], y31 = wp3[1];

        aA0 = fmaf(w00, y00 - y01, aA0);  aB0 += y01;
        aA1 = fmaf(w10, y10 - y11, aA1);  aB1 += y11;
        aA2 = fmaf(w20, y20 - y21, aA2);  aB2 += y21;
        aA3 = fmaf(w30, y30 - y31, aA3);  aB3 += y31;
    }

    // --- reduce across the 8 sensor-waves, 2 acc-sets per round
    const float a0 = aA0 + aB0, a1 = aA1 + aB1;
    const float a2 = aA2 + aB2, a3 = aA3 + aB3;
#pragma unroll
    for (int r = 0; r < 2; ++r) {
        part[0][tid] = (r == 0) ? a0 : a2;
        part[1][tid] = (r == 0) ? a1 : a3;
        __syncthreads();
        if (tid < 128) {
            const int kl = tid >> 6;        // which acc of this round
            const int l = tid & 63;
            float v = part[kl][l];
#pragma unroll
            for (int w = 1; w < 8; ++w) v += part[kl][w * 64 + l];
            const int row = ti * TI + (l >> 4) + 4 * (2 * r + kl);
            out[row * NY + (tj * TJ + (l & 15))] = v;
        }
        __syncthreads();
    }
}

extern "C" void kernel_launch(void* const* d_in, const int* in_sizes, int n_in,
                              void* d_out, int out_size, void* d_ws, size_t ws_size,
                              hipStream_t stream) {
    const float* x = (const float*)d_in[0];        // (1, NS, NT)
    const float* sensors = (const float*)d_in[1];  // (NS, 2)
    const float* grid = (const float*)d_in[2];     // (P, 2)
    float* out = (float*)d_out;                    // (1, NX, NY)

    const int nblocks = (NX / TI) * (NY / TJ);     // 1024 blocks, 512 threads
    das_kernel<<<nblocks, 512, 0, stream>>>(x, sensors, grid, out);
}